// Round 15
// baseline (266.551 us; speedup 1.0000x reference)
//
#include <hip/hip_runtime.h>
#include <math.h>

#define Bb 2
#define Tt 2048
#define Ssz 2048
#define Hh 16
#define Dd 64
#define Ee 1024

#define NQ  (Bb*Tt*Ee)
#define NKV (Bb*Ssz*Ee)
#define NW  (3*Ee*Ee)
#define NWO (Ee*Ee)

#define LOG2E 1.44269504088896f

typedef __bf16 bf16x8 __attribute__((ext_vector_type(8)));
typedef float  floatx4 __attribute__((ext_vector_type(4)));
typedef short  short4_ __attribute__((ext_vector_type(4)));
typedef unsigned short u16;
typedef unsigned int   u32;

__device__ __forceinline__ u16 f2bf(float f) {
    __bf16 h = (__bf16)f;
    union { __bf16 h; u16 u; } v; v.h = h; return v.u;
}
__device__ __forceinline__ float bf2f(u16 b) {
    union { u32 u; float f; } v; v.u = ((u32)b) << 16; return v.f;
}
__device__ __forceinline__ float load_f(const void* p, int i, bool isbf) {
    if (isbf) return bf2f(((const u16*)p)[i]);
    return ((const float*)p)[i];
}
__device__ __forceinline__ u32 load2(const void* p, int i, bool isbf) {
    if (isbf) return ((const u32*)p)[i >> 1];
    float2 f = ((const float2*)p)[i >> 1];
    return (u32)f2bf(f.x) | ((u32)f2bf(f.y) << 16);
}

typedef __attribute__((address_space(1))) const unsigned int gas_u32;
typedef __attribute__((address_space(3))) unsigned int las_u32;
__device__ __forceinline__ void gl_lds16(const u16* g, u16* l) {
    __builtin_amdgcn_global_load_lds((gas_u32*)g, (las_u32*)l, 16, 0, 0);
}

// XOR granule swizzle: 16B granules within each 64-elem chunk, g ^= (row&7).
__device__ __forceinline__ int swz(int k, int row) {
    return (k & ~63) | ((((k >> 3) ^ row) & 7) << 3) | (k & 7);
}

// ---------------- dtype detector ----------------
__global__ void k_detect(const u32* __restrict__ qw, int* __restrict__ flag) {
    __shared__ int cnt;
    if (threadIdx.x == 0) cnt = 0;
    __syncthreads();
    int h = 0;
    for (int i = threadIdx.x; i < 4096; i += 256) {
        u32 w = qw[i];
        u32 b = (w >> 8) & 0x7Fu;
        if ((b & 0x7Cu) == 0x3Cu) h++;
    }
    atomicAdd(&cnt, h);
    __syncthreads();
    if (threadIdx.x == 0) flag[0] = (cnt > 2048) ? 1 : 0;
}

// ---------------- pack/cast inputs to bf16 (swizzled), pair-vectorized ----------------
__global__ void k_pack(const void* __restrict__ q, const void* __restrict__ kv,
                       const void* __restrict__ w_in, const void* __restrict__ b_in,
                       const void* __restrict__ w_out, const void* __restrict__ b_out,
                       const int* __restrict__ flag,
                       u32* __restrict__ qb, u32* __restrict__ kb, u32* __restrict__ vb,
                       u32* __restrict__ wb, u32* __restrict__ wob, float* __restrict__ biases) {
    bool isbf = flag[0] != 0;
    int i = (blockIdx.x * 256 + threadIdx.x) * 2;
    if (i < NQ) { int row = i >> 10, k = i & 1023;
        qb[(((size_t)row << 10) | (u32)swz(k, row)) >> 1] = load2(q, i, isbf); return; }
    i -= NQ;
    if (i < NKV) { int row = i >> 10, e = i & 1023;
        kb[(((size_t)row << 10) | (u32)swz(e, row)) >> 1] = load2(kv, row*2048 + e, isbf); return; }
    i -= NKV;
    if (i < NKV) { int row = i >> 10, e = i & 1023;
        vb[(((size_t)row << 10) | (u32)swz(e, row)) >> 1] = load2(kv, row*2048 + 1024 + e, isbf); return; }
    i -= NKV;
    if (i < NW) { int row = i >> 10, k = i & 1023;
        wb[(((size_t)row << 10) | (u32)swz(k, row)) >> 1] = load2(w_in, i, isbf); return; }
    i -= NW;
    if (i < NWO) { int row = i >> 10, k = i & 1023;
        wob[(((size_t)row << 10) | (u32)swz(k, row)) >> 1] = load2(w_out, i, isbf); return; }
    i -= NWO;
    if (i < 3072) { biases[i] = load_f(b_in, i, isbf); biases[i+1] = load_f(b_in, i+1, isbf); return; }
    i -= 3072;
    if (i < 1024) { biases[3072+i] = load_f(b_out, i, isbf); biases[3072+i+1] = load_f(b_out, i+1, isbf); }
}

// ---------------- fused QKV projections: 128x128 tile, 512 threads, 8 waves of 64x32 --------
// Round-10: 768 blocks x 8 waves -> 3 blocks/CU, 24 waves/CU uniform. Confirmed. Mode-2 Vt
// epilogue XORs within-granule bit 2 with d's bit 3 (kills k_flash PV b64 4-way conflict —
// verified round 11: SQ_LDS_BANK_CONFLICT 4.26M -> 65K).
__global__ __launch_bounds__(512) void k_gemm_qkv(const u16* __restrict__ qb, const u16* __restrict__ kb,
                                                  const u16* __restrict__ vb, const u16* __restrict__ wb,
                                                  const float* __restrict__ biases,
                                                  u16* __restrict__ Qp, u16* __restrict__ Kp,
                                                  u16* __restrict__ Vt) {
    __shared__ u16 As[128 * 64];   // 16KB
    __shared__ u16 Ws[128 * 64];   // 16KB
    int flat = blockIdx.x + 8 * (blockIdx.y + 32 * blockIdx.z);   // HW dispatch order, x fastest
    int wg = (flat & 7) * 96 + (flat >> 3);                        // XCD-chunked bijective remap
    int mode = wg >> 8;
    int rem = wg & 255;
    int m0 = (rem >> 3) * 128;
    int n0 = (rem & 7) * 128;
    const u16* A = ((mode == 0) ? qb : (mode == 1) ? kb : vb) + (size_t)m0 * 1024;
    const u16* W = wb + (size_t)mode * Ee * Ee + (size_t)n0 * 1024;
    const float* bias = biases + mode * 1024;
    int tid = threadIdx.x, lane = tid & 63;
    int w = tid >> 6;                       // 0..7
    int q = lane >> 4, ml = lane & 15;
    int mh = (w >> 2) * 64;                 // 0 / 64
    int nh = (w & 3) * 32;                  // 0 / 32 / 64 / 96
    int rsw = tid >> 3, cs = (tid & 7) * 8; // rsw 0..63: one 64-row sweep per issue

    floatx4 acc[4][2];
#pragma unroll
    for (int a = 0; a < 4; ++a)
#pragma unroll
        for (int b2 = 0; b2 < 2; ++b2) acc[a][b2] = (floatx4){0.f, 0.f, 0.f, 0.f};

    for (int k0 = 0; k0 < 1024; k0 += 64) {
        __syncthreads();   // protect LDS from previous step's readers
#pragma unroll
        for (int j = 0; j < 2; ++j) {
            gl_lds16(A + (size_t)(j*64 + rsw) * 1024 + k0 + cs, &As[(j*64 + rsw)*64 + cs]);
            gl_lds16(W + (size_t)(j*64 + rsw) * 1024 + k0 + cs, &Ws[(j*64 + rsw)*64 + cs]);
        }
        __syncthreads();   // vmcnt(0) drain
#pragma unroll
        for (int kk = 0; kk < 2; ++kk) {
            int gs = (((kk*4 + q) ^ ml) & 7) * 8;
            bf16x8 af[4], bfv[2];
#pragma unroll
            for (int mt = 0; mt < 4; ++mt) af[mt]  = *(const bf16x8*)&As[(mh + mt*16 + ml)*64 + gs];
#pragma unroll
            for (int nt = 0; nt < 2; ++nt) bfv[nt] = *(const bf16x8*)&Ws[(nh + nt*16 + ml)*64 + gs];
#pragma unroll
            for (int mt = 0; mt < 4; ++mt)
#pragma unroll
                for (int nt = 0; nt < 2; ++nt)
                    acc[mt][nt] = __builtin_amdgcn_mfma_f32_16x16x32_bf16(af[mt], bfv[nt], acc[mt][nt], 0, 0, 0);
        }
    }

#pragma unroll
    for (int mt = 0; mt < 4; ++mt) {
#pragma unroll
        for (int nt = 0; nt < 2; ++nt) {
#pragma unroll
            for (int rg = 0; rg < 4; ++rg) {
                int m = m0 + mh + mt*16 + q*4 + rg;
                int n = n0 + nh + nt*16 + ml;
                float val = acc[mt][nt][rg] + bias[n];
                int b = m >> 11, t = m & 2047, hh = n >> 6, d = n & 63;
                if (mode == 0) {
                    int dsw = ((((d >> 3) ^ t) & 7) << 3) | (d & 7);
                    Qp[((size_t)(b*16 + hh) * 2048 + t) * 64 + dsw] = f2bf(val * (0.125f * LOG2E));
                } else if (mode == 1) {
                    int dsw = ((((d >> 3) ^ t) & 7) << 3) | (d & 7);
                    Kp[((size_t)(b*16 + hh) * 2048 + t) * 64 + dsw] = f2bf(val);
                } else {
                    // granule ^= d (bank spread) AND sub-bit2 ^= d bit 3 (kills the
                    // ml/ml^8 aliasing in k_flash's b64 PV reads: 4-way -> free 2-way)
                    int tsw = (t & ~63) | ((((t >> 3) ^ d) & 7) << 3)
                            | ((t & 7) ^ (((d >> 3) & 1) << 2));
                    Vt[((size_t)(b*16 + hh) * 64 + d) * 2048 + tsw] = f2bf(val);
                }
            }
        }
    }
}

// ---------------- out-projection: qkv-style single-buffer, 64x128 tiles, 512 threads -------
// Round-13: confirmed (dropped out of top-5). 16 waves/CU single-buffer chain.
__global__ __launch_bounds__(512) void k_gemm_out(const u16* __restrict__ A, const u16* __restrict__ W,
                                                  const float* __restrict__ bias, void* __restrict__ Cout,
                                                  const int* __restrict__ flag) {
    __shared__ u16 As[64 * 64];    // 8KB
    __shared__ u16 Ws[128 * 64];   // 16KB
    int flat = blockIdx.x + 8 * blockIdx.y;       // grid (8,64), x fastest
    int wg = (flat & 7) * 64 + (flat >> 3);       // XCD-chunked bijective (512%8==0)
    int m0 = (wg >> 3) * 64;
    int n0 = (wg & 7) * 128;
    const u16* Ab = A + (size_t)m0 * 1024;
    const u16* Wb = W + (size_t)n0 * 1024;
    int tid = threadIdx.x, lane = tid & 63;
    int w = tid >> 6;                       // 0..7
    int q = lane >> 4, ml = lane & 15;
    int mh = (w >> 2) * 32;                 // 0 / 32
    int nh = (w & 3) * 32;                  // 0 / 32 / 64 / 96
    int rsw = tid >> 3, cs = (tid & 7) * 8; // rsw 0..63

    floatx4 acc[2][2];
#pragma unroll
    for (int a = 0; a < 2; ++a)
#pragma unroll
        for (int b2 = 0; b2 < 2; ++b2) acc[a][b2] = (floatx4){0.f, 0.f, 0.f, 0.f};

    for (int k0 = 0; k0 < 1024; k0 += 64) {
        __syncthreads();
        gl_lds16(Ab + (size_t)rsw * 1024 + k0 + cs, &As[rsw*64 + cs]);
#pragma unroll
        for (int j = 0; j < 2; ++j)
            gl_lds16(Wb + (size_t)(j*64 + rsw) * 1024 + k0 + cs, &Ws[(j*64 + rsw)*64 + cs]);
        __syncthreads();   // vmcnt(0) drain
#pragma unroll
        for (int kk = 0; kk < 2; ++kk) {
            int gs = (((kk*4 + q) ^ ml) & 7) * 8;
            bf16x8 af[2], bfv[2];
#pragma unroll
            for (int mt = 0; mt < 2; ++mt) af[mt]  = *(const bf16x8*)&As[(mh + mt*16 + ml)*64 + gs];
#pragma unroll
            for (int nt = 0; nt < 2; ++nt) bfv[nt] = *(const bf16x8*)&Ws[(nh + nt*16 + ml)*64 + gs];
#pragma unroll
            for (int mt = 0; mt < 2; ++mt)
#pragma unroll
                for (int nt = 0; nt < 2; ++nt)
                    acc[mt][nt] = __builtin_amdgcn_mfma_f32_16x16x32_bf16(af[mt], bfv[nt], acc[mt][nt], 0, 0, 0);
        }
    }

    bool outbf = flag[0] != 0;
#pragma unroll
    for (int mt = 0; mt < 2; ++mt) {
#pragma unroll
        for (int nt = 0; nt < 2; ++nt) {
#pragma unroll
            for (int rg = 0; rg < 4; ++rg) {
                int m = m0 + mh + mt*16 + q*4 + rg;
                int n = n0 + nh + nt*16 + ml;
                float val = acc[mt][nt][rg] + bias[n];
                if (outbf) ((u16*)Cout)[(size_t)m * 1024 + n] = f2bf(val);
                else       ((float*)Cout)[(size_t)m * 1024 + n] = val;
            }
        }
    }
}

// ---------------- flash attention ctx: 128 q-rows/block, 8 waves = 4 row-teams x 2 s-teams ----
// Round-15: reverted to the round-13 structure (measured 50.9/50.2 twice). Round-14's 64-row
// tile regressed to 60us: halving the t-tile halves K/V staging REUSE (each block stages the
// full 2048-row K/V stream), so 1024 blocks doubled per-CU staging work — occupancy lever
// only pays when per-CU total work is constant. Added T5 s_setprio around MFMA clusters:
// 2 independent blocks/CU at different phases -> scheduler can prefer MFMA-entering waves
// (m191: +4-7% on attn-like kernels; neutral-to-negative only on lockstep single-block GEMM).
__global__ __launch_bounds__(512) void k_flash(const u16* __restrict__ Qp, const u16* __restrict__ Kp,
                                               const u16* __restrict__ Vt, u16* __restrict__ ctx,
                                               float* __restrict__ lbuf) {
    __shared__ u16 smem[3 * 64 * 128];          // [0,8192): Qs  [8192,16384): Ks dbuf  [16384,24576): Vs dbuf
    u16* Qs = smem;
    u16* KsB = smem + 8192;
    u16* VsB = smem + 16384;
    int flat = blockIdx.x + 16 * (blockIdx.y + 16 * blockIdx.z);  // HW dispatch order, x fastest
    int wg = (flat & 7) * 64 + (flat >> 3);                       // XCD-chunked bijective (512%8==0)
    int t0 = (wg & 15) * 128;
    int h  = (wg >> 4) & 15;
    int b  = wg >> 8;
    const u16* Qh = Qp + (size_t)(b*16 + h) * 2048 * 64;
    const u16* Kh = Kp + (size_t)(b*16 + h) * 2048 * 64;
    const u16* Vh = Vt + (size_t)(b*16 + h) * 64 * 2048;
    int tid = threadIdx.x, lane = tid & 63;
    int wv = tid >> 6, r = wv & 3, e = wv >> 2;
    int q = lane >> 4, ml = lane & 15;
    int rsw = tid >> 3, cs = (tid & 7) * 8;   // 512 threads: one 64-row sweep per issue

    // prologue: stage Q (2 sweeps) + first K/V tile (1 sweep each), one drain
#pragma unroll
    for (int j = 0; j < 2; ++j)
        gl_lds16(Qh + (size_t)(t0 + j*64 + rsw) * 64 + cs, &Qs[(j*64 + rsw)*64 + cs]);
    gl_lds16(Kh + (size_t)rsw * 64 + cs, &KsB[rsw*64 + cs]);
    gl_lds16(Vh + (size_t)rsw * 2048 + cs, &VsB[rsw*64 + cs]);
    __syncthreads();

    bf16x8 qf[2][2];
#pragma unroll
    for (int mt = 0; mt < 2; ++mt)
#pragma unroll
        for (int kk = 0; kk < 2; ++kk)
            qf[mt][kk] = *(const bf16x8*)&Qs[(r*32 + mt*16 + ml)*64 + (((kk*4 + q) ^ ml) & 7)*8];

    float lp[2] = {0.f, 0.f};                 // partial row-sums (this wave's s-half)
    floatx4 ct[2][4];
#pragma unroll
    for (int mt = 0; mt < 2; ++mt)
#pragma unroll
        for (int i = 0; i < 4; ++i) ct[mt][i] = (floatx4){0.f, 0.f, 0.f, 0.f};

    int cur = 0;
    for (int s0 = 0; s0 < 2048; s0 += 64) {
        if (s0 + 64 < 2048) {
            gl_lds16(Kh + (size_t)(s0 + 64 + rsw) * 64 + cs, &KsB[(cur ^ 1)*4096 + rsw*64 + cs]);
            gl_lds16(Vh + (size_t)rsw * 2048 + (s0 + 64) + cs, &VsB[(cur ^ 1)*4096 + rsw*64 + cs]);
        }
        const u16* Ksc = KsB + cur*4096;
        const u16* Vsc = VsB + cur*4096;

        // swapped QK^T over this wave's s-half: sc[mt][ntl] = P[s = e*32+ntl*16+q*4+rg][t = ml of mt tile]
        floatx4 sc[2][2];
#pragma unroll
        for (int mt = 0; mt < 2; ++mt)
#pragma unroll
            for (int i = 0; i < 2; ++i) sc[mt][i] = (floatx4){0.f, 0.f, 0.f, 0.f};
        __builtin_amdgcn_s_setprio(1);
#pragma unroll
        for (int kk = 0; kk < 2; ++kk) {
            int gs = (((kk*4 + q) ^ ml) & 7) * 8;
#pragma unroll
            for (int ntl = 0; ntl < 2; ++ntl) {
                bf16x8 kf = *(const bf16x8*)&Ksc[(e*32 + ntl*16 + ml)*64 + gs];
#pragma unroll
                for (int mt = 0; mt < 2; ++mt)
                    sc[mt][ntl] = __builtin_amdgcn_mfma_f32_16x16x32_bf16(kf, qf[mt][kk], sc[mt][ntl], 0, 0, 0);
            }
        }
        __builtin_amdgcn_s_setprio(0);

        // exp + pack to bf16 A-fragments, fully in registers
        short4_ pa[2][2];
#pragma unroll
        for (int mt = 0; mt < 2; ++mt) {
#pragma unroll
            for (int ntl = 0; ntl < 2; ++ntl) {
#pragma unroll
                for (int rg = 0; rg < 4; ++rg) {
                    float p = __builtin_amdgcn_exp2f(sc[mt][ntl][rg]);
                    lp[mt] += p;
                    pa[mt][ntl][rg] = (short)f2bf(p);
                }
            }
        }

        // PV over this wave's s-half; V-frag (b64) shared across mt.
        // half index = (q ^ (ml>>3)) & 1 matches the pack-time sub-bit2 XOR with d bit 3.
        __builtin_amdgcn_s_setprio(1);
#pragma unroll
        for (int ksl = 0; ksl < 2; ++ksl) {
#pragma unroll
            for (int nt = 0; nt < 4; ++nt) {
                const u16* vp = &Vsc[(nt*16 + ml)*64
                                     + (((((e*2 + ksl)*2 + (q >> 1)) ^ ml) & 7) << 3)
                                     + ((q ^ (ml >> 3)) & 1)*4];
                short4_ vf = *(const short4_*)vp;
#pragma unroll
                for (int mt = 0; mt < 2; ++mt)
                    ct[mt][nt] = __builtin_amdgcn_mfma_f32_16x16x16bf16_1k(pa[mt][ksl], vf, ct[mt][nt], 0, 0, 0);
            }
        }
        __builtin_amdgcn_s_setprio(0);

        __syncthreads();   // drains prefetch (vmcnt 0) + protects K/V rotation
        cur ^= 1;
    }

    // reduce lp over q-groups within the wave
#pragma unroll
    for (int mt = 0; mt < 2; ++mt) {
        lp[mt] += __shfl_xor(lp[mt], 16);
        lp[mt] += __shfl_xor(lp[mt], 32);
    }

    // cross-team combine through retired LDS: e=1 writes partials, e=0 adds.
    float* redc = (float*)(smem + 8192);   // 32KB (Ks+Vs region)
    float* redl = (float*)smem;            // Qs region
    int basec = r*2048 + lane*32;
    if (e == 1) {
#pragma unroll
        for (int mt = 0; mt < 2; ++mt)
#pragma unroll
            for (int nt = 0; nt < 4; ++nt) {
                int g = mt*4 + nt;
                *(floatx4*)&redc[basec + ((g ^ (lane & 7)) << 2)] = ct[mt][nt];
            }
        redl[(r*64 + lane)*2]     = lp[0];
        redl[(r*64 + lane)*2 + 1] = lp[1];
    }
    __syncthreads();
    if (e == 0) {
#pragma unroll
        for (int mt = 0; mt < 2; ++mt)
#pragma unroll
            for (int nt = 0; nt < 4; ++nt) {
                int g = mt*4 + nt;
                ct[mt][nt] += *(const floatx4*)&redc[basec + ((g ^ (lane & 7)) << 2)];
            }
        lp[0] += redl[(r*64 + lane)*2];
        lp[1] += redl[(r*64 + lane)*2 + 1];

        if (lane < 16) {
            size_t base = (size_t)(b*16 + h) * 2048 + t0 + r*32;
#pragma unroll
            for (int mt = 0; mt < 2; ++mt) lbuf[base + mt*16 + lane] = lp[mt];
        }

#pragma unroll
        for (int mt = 0; mt < 2; ++mt) {
            float il[4];
#pragma unroll
            for (int rg = 0; rg < 4; ++rg) il[rg] = 1.f / __shfl(lp[mt], q*4 + rg);
#pragma unroll
            for (int nt = 0; nt < 4; ++nt) {
#pragma unroll
                for (int rg = 0; rg < 4; ++rg) {
                    int t = t0 + r*32 + mt*16 + q*4 + rg;
                    int c64 = nt*16 + ml;
                    int col = h*64 + (((((c64 >> 3) ^ t) & 7)) << 3) + (c64 & 7);
                    ctx[(size_t)(b*2048 + t) * 1024 + col] = f2bf(ct[mt][nt][rg] * il[rg]);
                }
            }
        }
    }
}

// ---------------- attention weights: mean over heads; 128t x 128s per block, 512 threads ----
// Round-13: XCD-chunked remap kept (per-head working set Q 64KB + K 256KB L2-resident).
__global__ __launch_bounds__(512) void k_attnw(const u16* __restrict__ Qp, const u16* __restrict__ Kp,
                                               const float* __restrict__ lbuf,
                                               void* __restrict__ dout, const int* __restrict__ flag) {
    __shared__ u16 Qs[128 * 64];
    __shared__ u16 Ks[128 * 64];
    int flat = blockIdx.x + 16 * (blockIdx.y + 16 * blockIdx.z);  // grid (16,16,2), x fastest
    int wg = (flat & 7) * 64 + (flat >> 3);                       // XCD-chunked bijective (512%8==0)
    int s0 = (wg & 15) * 128;
    int t0 = ((wg >> 4) & 15) * 128;
    int b  = wg >> 8;
    int tid = threadIdx.x, lane = tid & 63;
    int w = tid >> 6, q = lane >> 4, ml = lane & 15;   // w 0..7: t-row team
    int rsw = tid >> 3, cs = (tid & 7) * 8;            // rsw 0..63: one 64-row sweep/issue

    floatx4 aw[8];
#pragma unroll
    for (int i = 0; i < 8; ++i) aw[i] = (floatx4){0.f, 0.f, 0.f, 0.f};

    for (int h = 0; h < 16; ++h) {
        const u16* Qh = Qp + (size_t)(b*16 + h) * 2048 * 64;
        const u16* Kh = Kp + (size_t)(b*16 + h) * 2048 * 64;
        __syncthreads();
#pragma unroll
        for (int j = 0; j < 2; ++j) {
            gl_lds16(Qh + (size_t)(t0 + j*64 + rsw) * 64 + cs, &Qs[(j*64 + rsw)*64 + cs]);
            gl_lds16(Kh + (size_t)(s0 + j*64 + rsw) * 64 + cs, &Ks[(j*64 + rsw)*64 + cs]);
        }
        __syncthreads();

        float il[4];
        size_t sb = (size_t)(b*16 + h) * 2048 + t0 + w*16 + q*4;
#pragma unroll
        for (int rg = 0; rg < 4; ++rg) il[rg] = 1.f / lbuf[sb + rg];

        floatx4 sc[8];
#pragma unroll
        for (int i = 0; i < 8; ++i) sc[i] = (floatx4){0.f, 0.f, 0.f, 0.f};
#pragma unroll
        for (int kk = 0; kk < 2; ++kk) {
            int gs = (((kk*4 + q) ^ ml) & 7) * 8;
            bf16x8 qfr = *(const bf16x8*)&Qs[(w*16 + ml)*64 + gs];
#pragma unroll
            for (int nt = 0; nt < 8; ++nt) {
                bf16x8 kfr = *(const bf16x8*)&Ks[(nt*16 + ml)*64 + gs];
                sc[nt] = __builtin_amdgcn_mfma_f32_16x16x32_bf16(qfr, kfr, sc[nt], 0, 0, 0);
            }
        }
#pragma unroll
        for (int nt = 0; nt < 8; ++nt)
#pragma unroll
            for (int rg = 0; rg < 4; ++rg)
                aw[nt][rg] += __builtin_amdgcn_exp2f(sc[nt][rg]) * il[rg];
    }

    bool outbf = flag[0] != 0;
    const size_t attn_base = (size_t)Bb * Tt * Ee;
#pragma unroll
    for (int nt = 0; nt < 8; ++nt) {
#pragma unroll
        for (int rg = 0; rg < 4; ++rg) {
            int t = t0 + w*16 + q*4 + rg;
            int s = s0 + nt*16 + ml;
            float val = aw[nt][rg] * 0.0625f;
            size_t idx = attn_base + (size_t)(b*2048 + t) * 2048 + s;
            if (outbf) ((u16*)dout)[idx] = f2bf(val);
            else       ((float*)dout)[idx] = val;
        }
    }
}

// ---------------- host launcher ----------------
extern "C" void kernel_launch(void* const* d_in, const int* in_sizes, int n_in,
                              void* d_out, int out_size, void* d_ws, size_t ws_size,
                              hipStream_t stream) {
    const void* q     = d_in[0];
    const void* kv    = d_in[1];
    const void* w_in  = d_in[2];
    const void* b_in  = d_in[3];
    const void* w_out = d_in[4];
    const void* b_out = d_in[5];

    char* ws = (char*)d_ws;
    size_t off = 0;
    auto alloc = [&](size_t bytes) -> void* {
        void* p = ws + off;
        off += (bytes + 255) & ~(size_t)255;
        return p;
    };
    int*   flag   = (int*)alloc(256);
    u16*   qb     = (u16*)alloc((size_t)NQ * 2);
    u16*   kb     = (u16*)alloc((size_t)NKV * 2);
    u16*   vb     = (u16*)alloc((size_t)NKV * 2);
    u16*   wb     = (u16*)alloc((size_t)NW * 2);
    u16*   wob    = (u16*)alloc((size_t)NWO * 2);
    float* biases = (float*)alloc(4096 * 4);
    u16*   Qp     = (u16*)alloc((size_t)NQ * 2);
    u16*   Kp     = (u16*)alloc((size_t)NKV * 2);
    u16*   Vt     = (u16*)alloc((size_t)NKV * 2);
    u16*   ctx    = (u16*)alloc((size_t)NQ * 2);
    float* lbuf   = (float*)alloc((size_t)Bb * Hh * Tt * 4);

    k_detect<<<1, 256, 0, stream>>>((const u32*)q, flag);

    int totalPairs = (NQ + NKV + NKV + NW + NWO + 4096) / 2;
    k_pack<<<(totalPairs + 255) / 256, 256, 0, stream>>>(q, kv, w_in, b_in, w_out, b_out, flag,
                                                         (u32*)qb, (u32*)kb, (u32*)vb,
                                                         (u32*)wb, (u32*)wob, biases);

    k_gemm_qkv<<<dim3(8, 32, 3), 512, 0, stream>>>(qb, kb, vb, wb, biases, Qp, Kp, Vt);

    k_flash<<<dim3(Tt / 128, Hh, Bb), 512, 0, stream>>>(Qp, Kp, Vt, ctx, lbuf);
    k_attnw<<<dim3(Ssz / 128, Tt / 128, Bb), 512, 0, stream>>>(Qp, Kp, lbuf, d_out, flag);

    k_gemm_out<<<dim3(8, 64), 512, 0, stream>>>(ctx, wob, biases + 3072, d_out, flag);
}

// Round 16
// 257.652 us; speedup vs baseline: 1.0345x; 1.0345x over previous
//
#include <hip/hip_runtime.h>
#include <math.h>

#define Bb 2
#define Tt 2048
#define Ssz 2048
#define Hh 16
#define Dd 64
#define Ee 1024

#define NQ  (Bb*Tt*Ee)
#define NKV (Bb*Ssz*Ee)
#define NW  (3*Ee*Ee)
#define NWO (Ee*Ee)

#define LOG2E 1.44269504088896f

typedef __bf16 bf16x8 __attribute__((ext_vector_type(8)));
typedef float  floatx4 __attribute__((ext_vector_type(4)));
typedef short  short4_ __attribute__((ext_vector_type(4)));
typedef unsigned short u16;
typedef unsigned int   u32;
typedef u32 u32x4 __attribute__((ext_vector_type(4)));

__device__ __forceinline__ u16 f2bf(float f) {
    __bf16 h = (__bf16)f;
    union { __bf16 h; u16 u; } v; v.h = h; return v.u;
}
__device__ __forceinline__ float bf2f(u16 b) {
    union { u32 u; float f; } v; v.u = ((u32)b) << 16; return v.f;
}
__device__ __forceinline__ float load_f(const void* p, int i, bool isbf) {
    if (isbf) return bf2f(((const u16*)p)[i]);
    return ((const float*)p)[i];
}
// load 8 consecutive elements as 8 packed bf16 (16B), vectorized both dtypes
__device__ __forceinline__ u32x4 load8(const void* p, size_t i, bool isbf) {
    if (isbf) return *(const u32x4*)((const u16*)p + i);
    const float4* f = (const float4*)((const float*)p + i);
    float4 a = f[0], b = f[1];
    u32x4 r;
    r.x = (u32)f2bf(a.x) | ((u32)f2bf(a.y) << 16);
    r.y = (u32)f2bf(a.z) | ((u32)f2bf(a.w) << 16);
    r.z = (u32)f2bf(b.x) | ((u32)f2bf(b.y) << 16);
    r.w = (u32)f2bf(b.z) | ((u32)f2bf(b.w) << 16);
    return r;
}

typedef __attribute__((address_space(1))) const unsigned int gas_u32;
typedef __attribute__((address_space(3))) unsigned int las_u32;
__device__ __forceinline__ void gl_lds16(const u16* g, u16* l) {
    __builtin_amdgcn_global_load_lds((gas_u32*)g, (las_u32*)l, 16, 0, 0);
}

// XOR granule swizzle: 16B granules within each 64-elem chunk, g ^= (row&7).
__device__ __forceinline__ int swz(int k, int row) {
    return (k & ~63) | ((((k >> 3) ^ row) & 7) << 3) | (k & 7);
}

// ---------------- dtype detector ----------------
__global__ void k_detect(const u32* __restrict__ qw, int* __restrict__ flag) {
    __shared__ int cnt;
    if (threadIdx.x == 0) cnt = 0;
    __syncthreads();
    int h = 0;
    for (int i = threadIdx.x; i < 4096; i += 256) {
        u32 w = qw[i];
        u32 b = (w >> 8) & 0x7Fu;
        if ((b & 0x7Cu) == 0x3Cu) h++;
    }
    atomicAdd(&cnt, h);
    __syncthreads();
    if (threadIdx.x == 0) flag[0] = (cnt > 2048) ? 1 : 0;
}

// ---------------- pack/cast inputs to bf16 (swizzled), 8 elems (1 granule) per thread ------
// Round-16: previous version stored 4B per thread (Common-mistake #2). The granule swizzle
// permutes 16B granules intact (k&7 preserved), so 8 aligned elements map to ONE 16B store
// at the swizzled granule: float4 x2 loads + u32x4 store, fully coalesced both sides.
__global__ void k_pack(const void* __restrict__ q, const void* __restrict__ kv,
                       const void* __restrict__ w_in, const void* __restrict__ b_in,
                       const void* __restrict__ w_out, const void* __restrict__ b_out,
                       const int* __restrict__ flag,
                       u16* __restrict__ qb, u16* __restrict__ kb, u16* __restrict__ vb,
                       u16* __restrict__ wb, u16* __restrict__ wob, float* __restrict__ biases) {
    bool isbf = flag[0] != 0;
    long long i = ((long long)blockIdx.x * 256 + threadIdx.x) * 8;
    if (i < NQ) { int row = (int)(i >> 10), k = (int)(i & 1023);
        *(u32x4*)&qb[((size_t)row << 10) | (u32)swz(k, row)] = load8(q, i, isbf); return; }
    i -= NQ;
    if (i < NKV) { int row = (int)(i >> 10), e = (int)(i & 1023);
        *(u32x4*)&kb[((size_t)row << 10) | (u32)swz(e, row)] = load8(kv, (size_t)row*2048 + e, isbf); return; }
    i -= NKV;
    if (i < NKV) { int row = (int)(i >> 10), e = (int)(i & 1023);
        *(u32x4*)&vb[((size_t)row << 10) | (u32)swz(e, row)] = load8(kv, (size_t)row*2048 + 1024 + e, isbf); return; }
    i -= NKV;
    if (i < NW) { int row = (int)(i >> 10), k = (int)(i & 1023);
        *(u32x4*)&wb[((size_t)row << 10) | (u32)swz(k, row)] = load8(w_in, i, isbf); return; }
    i -= NW;
    if (i < NWO) { int row = (int)(i >> 10), k = (int)(i & 1023);
        *(u32x4*)&wob[((size_t)row << 10) | (u32)swz(k, row)] = load8(w_out, i, isbf); return; }
    i -= NWO;
    if (i < 3072) {
#pragma unroll
        for (int j = 0; j < 8; ++j) biases[i + j] = load_f(b_in, (int)i + j, isbf);
        return;
    }
    i -= 3072;
    if (i < 1024) {
#pragma unroll
        for (int j = 0; j < 8; ++j) biases[3072 + i + j] = load_f(b_out, (int)i + j, isbf);
    }
}

// ---------------- fused QKV projections: 128x128 tile, 512 threads, 8 waves of 64x32 --------
// Round-10: 768 blocks x 8 waves -> 3 blocks/CU, 24 waves/CU uniform. Confirmed. Mode-2 Vt
// epilogue XORs within-granule bit 2 with d's bit 3 (kills k_flash PV b64 4-way conflict —
// verified round 11: SQ_LDS_BANK_CONFLICT 4.26M -> 65K).
__global__ __launch_bounds__(512) void k_gemm_qkv(const u16* __restrict__ qb, const u16* __restrict__ kb,
                                                  const u16* __restrict__ vb, const u16* __restrict__ wb,
                                                  const float* __restrict__ biases,
                                                  u16* __restrict__ Qp, u16* __restrict__ Kp,
                                                  u16* __restrict__ Vt) {
    __shared__ u16 As[128 * 64];   // 16KB
    __shared__ u16 Ws[128 * 64];   // 16KB
    int flat = blockIdx.x + 8 * (blockIdx.y + 32 * blockIdx.z);   // HW dispatch order, x fastest
    int wg = (flat & 7) * 96 + (flat >> 3);                        // XCD-chunked bijective remap
    int mode = wg >> 8;
    int rem = wg & 255;
    int m0 = (rem >> 3) * 128;
    int n0 = (rem & 7) * 128;
    const u16* A = ((mode == 0) ? qb : (mode == 1) ? kb : vb) + (size_t)m0 * 1024;
    const u16* W = wb + (size_t)mode * Ee * Ee + (size_t)n0 * 1024;
    const float* bias = biases + mode * 1024;
    int tid = threadIdx.x, lane = tid & 63;
    int w = tid >> 6;                       // 0..7
    int q = lane >> 4, ml = lane & 15;
    int mh = (w >> 2) * 64;                 // 0 / 64
    int nh = (w & 3) * 32;                  // 0 / 32 / 64 / 96
    int rsw = tid >> 3, cs = (tid & 7) * 8; // rsw 0..63: one 64-row sweep per issue

    floatx4 acc[4][2];
#pragma unroll
    for (int a = 0; a < 4; ++a)
#pragma unroll
        for (int b2 = 0; b2 < 2; ++b2) acc[a][b2] = (floatx4){0.f, 0.f, 0.f, 0.f};

    for (int k0 = 0; k0 < 1024; k0 += 64) {
        __syncthreads();   // protect LDS from previous step's readers
#pragma unroll
        for (int j = 0; j < 2; ++j) {
            gl_lds16(A + (size_t)(j*64 + rsw) * 1024 + k0 + cs, &As[(j*64 + rsw)*64 + cs]);
            gl_lds16(W + (size_t)(j*64 + rsw) * 1024 + k0 + cs, &Ws[(j*64 + rsw)*64 + cs]);
        }
        __syncthreads();   // vmcnt(0) drain
#pragma unroll
        for (int kk = 0; kk < 2; ++kk) {
            int gs = (((kk*4 + q) ^ ml) & 7) * 8;
            bf16x8 af[4], bfv[2];
#pragma unroll
            for (int mt = 0; mt < 4; ++mt) af[mt]  = *(const bf16x8*)&As[(mh + mt*16 + ml)*64 + gs];
#pragma unroll
            for (int nt = 0; nt < 2; ++nt) bfv[nt] = *(const bf16x8*)&Ws[(nh + nt*16 + ml)*64 + gs];
#pragma unroll
            for (int mt = 0; mt < 4; ++mt)
#pragma unroll
                for (int nt = 0; nt < 2; ++nt)
                    acc[mt][nt] = __builtin_amdgcn_mfma_f32_16x16x32_bf16(af[mt], bfv[nt], acc[mt][nt], 0, 0, 0);
        }
    }

#pragma unroll
    for (int mt = 0; mt < 4; ++mt) {
#pragma unroll
        for (int nt = 0; nt < 2; ++nt) {
#pragma unroll
            for (int rg = 0; rg < 4; ++rg) {
                int m = m0 + mh + mt*16 + q*4 + rg;
                int n = n0 + nh + nt*16 + ml;
                float val = acc[mt][nt][rg] + bias[n];
                int b = m >> 11, t = m & 2047, hh = n >> 6, d = n & 63;
                if (mode == 0) {
                    int dsw = ((((d >> 3) ^ t) & 7) << 3) | (d & 7);
                    Qp[((size_t)(b*16 + hh) * 2048 + t) * 64 + dsw] = f2bf(val * (0.125f * LOG2E));
                } else if (mode == 1) {
                    int dsw = ((((d >> 3) ^ t) & 7) << 3) | (d & 7);
                    Kp[((size_t)(b*16 + hh) * 2048 + t) * 64 + dsw] = f2bf(val);
                } else {
                    // granule ^= d (bank spread) AND sub-bit2 ^= d bit 3 (kills the
                    // ml/ml^8 aliasing in k_flash's b64 PV reads: 4-way -> free 2-way)
                    int tsw = (t & ~63) | ((((t >> 3) ^ d) & 7) << 3)
                            | ((t & 7) ^ (((d >> 3) & 1) << 2));
                    Vt[((size_t)(b*16 + hh) * 64 + d) * 2048 + tsw] = f2bf(val);
                }
            }
        }
    }
}

// ---------------- out-projection: qkv-style single-buffer, 64x128 tiles, 512 threads -------
// Round-13: confirmed (dropped out of top-5). 16 waves/CU single-buffer chain.
__global__ __launch_bounds__(512) void k_gemm_out(const u16* __restrict__ A, const u16* __restrict__ W,
                                                  const float* __restrict__ bias, void* __restrict__ Cout,
                                                  const int* __restrict__ flag) {
    __shared__ u16 As[64 * 64];    // 8KB
    __shared__ u16 Ws[128 * 64];   // 16KB
    int flat = blockIdx.x + 8 * blockIdx.y;       // grid (8,64), x fastest
    int wg = (flat & 7) * 64 + (flat >> 3);       // XCD-chunked bijective (512%8==0)
    int m0 = (wg >> 3) * 64;
    int n0 = (wg & 7) * 128;
    const u16* Ab = A + (size_t)m0 * 1024;
    const u16* Wb = W + (size_t)n0 * 1024;
    int tid = threadIdx.x, lane = tid & 63;
    int w = tid >> 6;                       // 0..7
    int q = lane >> 4, ml = lane & 15;
    int mh = (w >> 2) * 32;                 // 0 / 32
    int nh = (w & 3) * 32;                  // 0 / 32 / 64 / 96
    int rsw = tid >> 3, cs = (tid & 7) * 8; // rsw 0..63

    floatx4 acc[2][2];
#pragma unroll
    for (int a = 0; a < 2; ++a)
#pragma unroll
        for (int b2 = 0; b2 < 2; ++b2) acc[a][b2] = (floatx4){0.f, 0.f, 0.f, 0.f};

    for (int k0 = 0; k0 < 1024; k0 += 64) {
        __syncthreads();
        gl_lds16(Ab + (size_t)rsw * 1024 + k0 + cs, &As[rsw*64 + cs]);
#pragma unroll
        for (int j = 0; j < 2; ++j)
            gl_lds16(Wb + (size_t)(j*64 + rsw) * 1024 + k0 + cs, &Ws[(j*64 + rsw)*64 + cs]);
        __syncthreads();   // vmcnt(0) drain
#pragma unroll
        for (int kk = 0; kk < 2; ++kk) {
            int gs = (((kk*4 + q) ^ ml) & 7) * 8;
            bf16x8 af[2], bfv[2];
#pragma unroll
            for (int mt = 0; mt < 2; ++mt) af[mt]  = *(const bf16x8*)&As[(mh + mt*16 + ml)*64 + gs];
#pragma unroll
            for (int nt = 0; nt < 2; ++nt) bfv[nt] = *(const bf16x8*)&Ws[(nh + nt*16 + ml)*64 + gs];
#pragma unroll
            for (int mt = 0; mt < 2; ++mt)
#pragma unroll
                for (int nt = 0; nt < 2; ++nt)
                    acc[mt][nt] = __builtin_amdgcn_mfma_f32_16x16x32_bf16(af[mt], bfv[nt], acc[mt][nt], 0, 0, 0);
        }
    }

    bool outbf = flag[0] != 0;
#pragma unroll
    for (int mt = 0; mt < 2; ++mt) {
#pragma unroll
        for (int nt = 0; nt < 2; ++nt) {
#pragma unroll
            for (int rg = 0; rg < 4; ++rg) {
                int m = m0 + mh + mt*16 + q*4 + rg;
                int n = n0 + nh + nt*16 + ml;
                float val = acc[mt][nt][rg] + bias[n];
                if (outbf) ((u16*)Cout)[(size_t)m * 1024 + n] = f2bf(val);
                else       ((float*)Cout)[(size_t)m * 1024 + n] = val;
            }
        }
    }
}

// ---------------- flash attention ctx: 128 q-rows/block, 8 waves = 4 row-teams x 2 s-teams ----
// Round-16: EXACT round-13 structure (measured 50.2/50.9/51.0 across three machines).
// Round-15's setprio regressed it (54.0 on a faster machine): our 8 waves are in barrier
// lockstep (the m190 GEMM null case), not independent-phase (the m191 attn win case).
// Keeps: XCD-chunked remap (FETCH 69.7 -> 12.3MB) + conflict-free V sub-granule swizzle.
__global__ __launch_bounds__(512) void k_flash(const u16* __restrict__ Qp, const u16* __restrict__ Kp,
                                               const u16* __restrict__ Vt, u16* __restrict__ ctx,
                                               float* __restrict__ lbuf) {
    __shared__ u16 smem[3 * 64 * 128];          // [0,8192): Qs  [8192,16384): Ks dbuf  [16384,24576): Vs dbuf
    u16* Qs = smem;
    u16* KsB = smem + 8192;
    u16* VsB = smem + 16384;
    int flat = blockIdx.x + 16 * (blockIdx.y + 16 * blockIdx.z);  // HW dispatch order, x fastest
    int wg = (flat & 7) * 64 + (flat >> 3);                       // XCD-chunked bijective (512%8==0)
    int t0 = (wg & 15) * 128;
    int h  = (wg >> 4) & 15;
    int b  = wg >> 8;
    const u16* Qh = Qp + (size_t)(b*16 + h) * 2048 * 64;
    const u16* Kh = Kp + (size_t)(b*16 + h) * 2048 * 64;
    const u16* Vh = Vt + (size_t)(b*16 + h) * 64 * 2048;
    int tid = threadIdx.x, lane = tid & 63;
    int wv = tid >> 6, r = wv & 3, e = wv >> 2;
    int q = lane >> 4, ml = lane & 15;
    int rsw = tid >> 3, cs = (tid & 7) * 8;   // 512 threads: one 64-row sweep per issue

    // prologue: stage Q (2 sweeps) + first K/V tile (1 sweep each), one drain
#pragma unroll
    for (int j = 0; j < 2; ++j)
        gl_lds16(Qh + (size_t)(t0 + j*64 + rsw) * 64 + cs, &Qs[(j*64 + rsw)*64 + cs]);
    gl_lds16(Kh + (size_t)rsw * 64 + cs, &KsB[rsw*64 + cs]);
    gl_lds16(Vh + (size_t)rsw * 2048 + cs, &VsB[rsw*64 + cs]);
    __syncthreads();

    bf16x8 qf[2][2];
#pragma unroll
    for (int mt = 0; mt < 2; ++mt)
#pragma unroll
        for (int kk = 0; kk < 2; ++kk)
            qf[mt][kk] = *(const bf16x8*)&Qs[(r*32 + mt*16 + ml)*64 + (((kk*4 + q) ^ ml) & 7)*8];

    float lp[2] = {0.f, 0.f};                 // partial row-sums (this wave's s-half)
    floatx4 ct[2][4];
#pragma unroll
    for (int mt = 0; mt < 2; ++mt)
#pragma unroll
        for (int i = 0; i < 4; ++i) ct[mt][i] = (floatx4){0.f, 0.f, 0.f, 0.f};

    int cur = 0;
    for (int s0 = 0; s0 < 2048; s0 += 64) {
        if (s0 + 64 < 2048) {
            gl_lds16(Kh + (size_t)(s0 + 64 + rsw) * 64 + cs, &KsB[(cur ^ 1)*4096 + rsw*64 + cs]);
            gl_lds16(Vh + (size_t)rsw * 2048 + (s0 + 64) + cs, &VsB[(cur ^ 1)*4096 + rsw*64 + cs]);
        }
        const u16* Ksc = KsB + cur*4096;
        const u16* Vsc = VsB + cur*4096;

        // swapped QK^T over this wave's s-half: sc[mt][ntl] = P[s = e*32+ntl*16+q*4+rg][t = ml of mt tile]
        floatx4 sc[2][2];
#pragma unroll
        for (int mt = 0; mt < 2; ++mt)
#pragma unroll
            for (int i = 0; i < 2; ++i) sc[mt][i] = (floatx4){0.f, 0.f, 0.f, 0.f};
#pragma unroll
        for (int kk = 0; kk < 2; ++kk) {
            int gs = (((kk*4 + q) ^ ml) & 7) * 8;
#pragma unroll
            for (int ntl = 0; ntl < 2; ++ntl) {
                bf16x8 kf = *(const bf16x8*)&Ksc[(e*32 + ntl*16 + ml)*64 + gs];
#pragma unroll
                for (int mt = 0; mt < 2; ++mt)
                    sc[mt][ntl] = __builtin_amdgcn_mfma_f32_16x16x32_bf16(kf, qf[mt][kk], sc[mt][ntl], 0, 0, 0);
            }
        }

        // exp + pack to bf16 A-fragments, fully in registers
        short4_ pa[2][2];
#pragma unroll
        for (int mt = 0; mt < 2; ++mt) {
#pragma unroll
            for (int ntl = 0; ntl < 2; ++ntl) {
#pragma unroll
                for (int rg = 0; rg < 4; ++rg) {
                    float p = __builtin_amdgcn_exp2f(sc[mt][ntl][rg]);
                    lp[mt] += p;
                    pa[mt][ntl][rg] = (short)f2bf(p);
                }
            }
        }

        // PV over this wave's s-half; V-frag (b64) shared across mt.
        // half index = (q ^ (ml>>3)) & 1 matches the pack-time sub-bit2 XOR with d bit 3.
#pragma unroll
        for (int ksl = 0; ksl < 2; ++ksl) {
#pragma unroll
            for (int nt = 0; nt < 4; ++nt) {
                const u16* vp = &Vsc[(nt*16 + ml)*64
                                     + (((((e*2 + ksl)*2 + (q >> 1)) ^ ml) & 7) << 3)
                                     + ((q ^ (ml >> 3)) & 1)*4];
                short4_ vf = *(const short4_*)vp;
#pragma unroll
                for (int mt = 0; mt < 2; ++mt)
                    ct[mt][nt] = __builtin_amdgcn_mfma_f32_16x16x16bf16_1k(pa[mt][ksl], vf, ct[mt][nt], 0, 0, 0);
            }
        }

        __syncthreads();   // drains prefetch (vmcnt 0) + protects K/V rotation
        cur ^= 1;
    }

    // reduce lp over q-groups within the wave
#pragma unroll
    for (int mt = 0; mt < 2; ++mt) {
        lp[mt] += __shfl_xor(lp[mt], 16);
        lp[mt] += __shfl_xor(lp[mt], 32);
    }

    // cross-team combine through retired LDS: e=1 writes partials, e=0 adds.
    float* redc = (float*)(smem + 8192);   // 32KB (Ks+Vs region)
    float* redl = (float*)smem;            // Qs region
    int basec = r*2048 + lane*32;
    if (e == 1) {
#pragma unroll
        for (int mt = 0; mt < 2; ++mt)
#pragma unroll
            for (int nt = 0; nt < 4; ++nt) {
                int g = mt*4 + nt;
                *(floatx4*)&redc[basec + ((g ^ (lane & 7)) << 2)] = ct[mt][nt];
            }
        redl[(r*64 + lane)*2]     = lp[0];
        redl[(r*64 + lane)*2 + 1] = lp[1];
    }
    __syncthreads();
    if (e == 0) {
#pragma unroll
        for (int mt = 0; mt < 2; ++mt)
#pragma unroll
            for (int nt = 0; nt < 4; ++nt) {
                int g = mt*4 + nt;
                ct[mt][nt] += *(const floatx4*)&redc[basec + ((g ^ (lane & 7)) << 2)];
            }
        lp[0] += redl[(r*64 + lane)*2];
        lp[1] += redl[(r*64 + lane)*2 + 1];

        if (lane < 16) {
            size_t base = (size_t)(b*16 + h) * 2048 + t0 + r*32;
#pragma unroll
            for (int mt = 0; mt < 2; ++mt) lbuf[base + mt*16 + lane] = lp[mt];
        }

#pragma unroll
        for (int mt = 0; mt < 2; ++mt) {
            float il[4];
#pragma unroll
            for (int rg = 0; rg < 4; ++rg) il[rg] = 1.f / __shfl(lp[mt], q*4 + rg);
#pragma unroll
            for (int nt = 0; nt < 4; ++nt) {
#pragma unroll
                for (int rg = 0; rg < 4; ++rg) {
                    int t = t0 + r*32 + mt*16 + q*4 + rg;
                    int c64 = nt*16 + ml;
                    int col = h*64 + (((((c64 >> 3) ^ t) & 7)) << 3) + (c64 & 7);
                    ctx[(size_t)(b*2048 + t) * 1024 + col] = f2bf(ct[mt][nt][rg] * il[rg]);
                }
            }
        }
    }
}

// ---------------- attention weights: mean over heads; 128t x 128s per block, 512 threads ----
// Round-13: XCD-chunked remap kept (per-head working set Q 64KB + K 256KB L2-resident).
__global__ __launch_bounds__(512) void k_attnw(const u16* __restrict__ Qp, const u16* __restrict__ Kp,
                                               const float* __restrict__ lbuf,
                                               void* __restrict__ dout, const int* __restrict__ flag) {
    __shared__ u16 Qs[128 * 64];
    __shared__ u16 Ks[128 * 64];
    int flat = blockIdx.x + 16 * (blockIdx.y + 16 * blockIdx.z);  // grid (16,16,2), x fastest
    int wg = (flat & 7) * 64 + (flat >> 3);                       // XCD-chunked bijective (512%8==0)
    int s0 = (wg & 15) * 128;
    int t0 = ((wg >> 4) & 15) * 128;
    int b  = wg >> 8;
    int tid = threadIdx.x, lane = tid & 63;
    int w = tid >> 6, q = lane >> 4, ml = lane & 15;   // w 0..7: t-row team
    int rsw = tid >> 3, cs = (tid & 7) * 8;            // rsw 0..63: one 64-row sweep/issue

    floatx4 aw[8];
#pragma unroll
    for (int i = 0; i < 8; ++i) aw[i] = (floatx4){0.f, 0.f, 0.f, 0.f};

    for (int h = 0; h < 16; ++h) {
        const u16* Qh = Qp + (size_t)(b*16 + h) * 2048 * 64;
        const u16* Kh = Kp + (size_t)(b*16 + h) * 2048 * 64;
        __syncthreads();
#pragma unroll
        for (int j = 0; j < 2; ++j) {
            gl_lds16(Qh + (size_t)(t0 + j*64 + rsw) * 64 + cs, &Qs[(j*64 + rsw)*64 + cs]);
            gl_lds16(Kh + (size_t)(s0 + j*64 + rsw) * 64 + cs, &Ks[(j*64 + rsw)*64 + cs]);
        }
        __syncthreads();

        float il[4];
        size_t sb = (size_t)(b*16 + h) * 2048 + t0 + w*16 + q*4;
#pragma unroll
        for (int rg = 0; rg < 4; ++rg) il[rg] = 1.f / lbuf[sb + rg];

        floatx4 sc[8];
#pragma unroll
        for (int i = 0; i < 8; ++i) sc[i] = (floatx4){0.f, 0.f, 0.f, 0.f};
#pragma unroll
        for (int kk = 0; kk < 2; ++kk) {
            int gs = (((kk*4 + q) ^ ml) & 7) * 8;
            bf16x8 qfr = *(const bf16x8*)&Qs[(w*16 + ml)*64 + gs];
#pragma unroll
            for (int nt = 0; nt < 8; ++nt) {
                bf16x8 kfr = *(const bf16x8*)&Ks[(nt*16 + ml)*64 + gs];
                sc[nt] = __builtin_amdgcn_mfma_f32_16x16x32_bf16(qfr, kfr, sc[nt], 0, 0, 0);
            }
        }
#pragma unroll
        for (int nt = 0; nt < 8; ++nt)
#pragma unroll
            for (int rg = 0; rg < 4; ++rg)
                aw[nt][rg] += __builtin_amdgcn_exp2f(sc[nt][rg]) * il[rg];
    }

    bool outbf = flag[0] != 0;
    const size_t attn_base = (size_t)Bb * Tt * Ee;
#pragma unroll
    for (int nt = 0; nt < 8; ++nt) {
#pragma unroll
        for (int rg = 0; rg < 4; ++rg) {
            int t = t0 + w*16 + q*4 + rg;
            int s = s0 + nt*16 + ml;
            float val = aw[nt][rg] * 0.0625f;
            size_t idx = attn_base + (size_t)(b*2048 + t) * 2048 + s;
            if (outbf) ((u16*)dout)[idx] = f2bf(val);
            else       ((float*)dout)[idx] = val;
        }
    }
}

// ---------------- host launcher ----------------
extern "C" void kernel_launch(void* const* d_in, const int* in_sizes, int n_in,
                              void* d_out, int out_size, void* d_ws, size_t ws_size,
                              hipStream_t stream) {
    const void* q     = d_in[0];
    const void* kv    = d_in[1];
    const void* w_in  = d_in[2];
    const void* b_in  = d_in[3];
    const void* w_out = d_in[4];
    const void* b_out = d_in[5];

    char* ws = (char*)d_ws;
    size_t off = 0;
    auto alloc = [&](size_t bytes) -> void* {
        void* p = ws + off;
        off += (bytes + 255) & ~(size_t)255;
        return p;
    };
    int*   flag   = (int*)alloc(256);
    u16*   qb     = (u16*)alloc((size_t)NQ * 2);
    u16*   kb     = (u16*)alloc((size_t)NKV * 2);
    u16*   vb     = (u16*)alloc((size_t)NKV * 2);
    u16*   wb     = (u16*)alloc((size_t)NW * 2);
    u16*   wob    = (u16*)alloc((size_t)NWO * 2);
    float* biases = (float*)alloc(4096 * 4);
    u16*   Qp     = (u16*)alloc((size_t)NQ * 2);
    u16*   Kp     = (u16*)alloc((size_t)NKV * 2);
    u16*   Vt     = (u16*)alloc((size_t)NKV * 2);
    u16*   ctx    = (u16*)alloc((size_t)NQ * 2);
    float* lbuf   = (float*)alloc((size_t)Bb * Hh * Tt * 4);

    k_detect<<<1, 256, 0, stream>>>((const u32*)q, flag);

    long long totalElems = (long long)NQ + NKV + NKV + NW + NWO + 4096;
    int packBlocks = (int)((totalElems / 8 + 255) / 256);
    k_pack<<<packBlocks, 256, 0, stream>>>(q, kv, w_in, b_in, w_out, b_out, flag,
                                           qb, kb, vb, wb, wob, biases);

    k_gemm_qkv<<<dim3(8, 32, 3), 512, 0, stream>>>(qb, kb, vb, wb, biases, Qp, Kp, Vt);

    k_flash<<<dim3(Tt / 128, Hh, Bb), 512, 0, stream>>>(Qp, Kp, Vt, ctx, lbuf);
    k_attnw<<<dim3(Ssz / 128, Tt / 128, Bb), 512, 0, stream>>>(Qp, Kp, lbuf, d_out, flag);

    k_gemm_out<<<dim3(8, 64), 512, 0, stream>>>(ctx, wob, biases + 3072, d_out, flag);
}